// Round 13
// baseline (116.584 us; speedup 1.0000x reference)
//
#include <hip/hip_runtime.h>
#include <hip/hip_bf16.h>
#include <stdint.h>

// Problem constants: B=8, S=1024, D=1024, H=16, DH=64
typedef __bf16 bf16_t;
typedef bf16_t bf16x8 __attribute__((ext_vector_type(8)));
typedef float f32x4 __attribute__((ext_vector_type(4)));
typedef unsigned short ushortx8 __attribute__((ext_vector_type(8)));

__device__ __forceinline__ uint16_t f2bf(float f) {
  uint32_t u = __float_as_uint(f);
  uint32_t r = u + 0x7FFFu + ((u >> 16) & 1u);  // RNE
  return (uint16_t)(r >> 16);
}

__device__ __forceinline__ int read_len(const int* __restrict__ p, int b) {
  bool is64 = (p[1] == 0) | (p[3] == 0) | (p[5] == 0) | (p[7] == 0);
  return is64 ? p[2 * b] : p[b];
}

#define GLDS16(gp, lp)                                                   \
  __builtin_amdgcn_global_load_lds(                                      \
      (const __attribute__((address_space(1))) uint32_t*)(gp),           \
      (__attribute__((address_space(3))) uint32_t*)(lp), 16, 0, 0)

// ------ f32 -> bf16 convert, weights only (wq 1M + wkv 2M elems) ------
__global__ void cvt2_kernel(const float* __restrict__ s0, uint16_t* __restrict__ d0, int n0,
                            const float* __restrict__ s1, uint16_t* __restrict__ d1, int n1) {
  int e = (blockIdx.x * blockDim.x + threadIdx.x) * 4;
  const float* s;
  uint16_t* d;
  if (e < n0) { s = s0 + e; d = d0 + e; }
  else if ((e -= n0) < n1) { s = s1 + e; d = d1 + e; }
  else return;
  const float4 v = *reinterpret_cast<const float4*>(s);
  ushort4 o;
  o.x = f2bf(v.x); o.y = f2bf(v.y); o.z = f2bf(v.z); o.w = f2bf(v.w);
  *reinterpret_cast<ushort4*>(d) = o;
}

// -------- Fused NT GEMM: Q = fr@wq^T+bq (scaled), KV = en@wkv^T+bkv --------
// 1536 blocks. Balanced XCD mapping (r11): unit (matrix, batch b, m-tile i)
// lands on XCD (b+i)&7. 2-phase dbuf (r9); length early-exit (r10).
// A: f32 activations reg-staged (T14: load early, convert+ds_write after
// compute) with swizzled ds_write. B: bf16 weights via global_load_lds with
// pre-swizzled source. LDS reads XOR-swizzled byte ^= (row&7)<<4.
__global__ __launch_bounds__(256) void gemm_fused(
    const float* __restrict__ frF, const float* __restrict__ enF,
    const uint16_t* __restrict__ wq, const uint16_t* __restrict__ wkv,
    const float* __restrict__ bq, const float* __restrict__ bkv,
    const int* __restrict__ l_en_p, const int* __restrict__ l_fr_p,
    uint16_t* __restrict__ Qb,       // [B,H,S,DH] bf16, pre-scaled
    uint16_t* __restrict__ Kb,       // [B,H,S,DH] bf16
    uint16_t* __restrict__ Vb) {     // [B,H,DH,S] bf16
  __shared__ __attribute__((aligned(16))) uint16_t As[2][128 * 64];
  __shared__ __attribute__((aligned(16))) uint16_t Bs[2][128 * 64];
  const int t = threadIdx.x;
  const int lane = t & 63;
  const int w = t >> 6;
  const int wm = w >> 1, wn = w & 1;
  const int l15 = lane & 15, lg = lane >> 4;

  const int orig = blockIdx.x;                 // 1536 = 8 xcd * 192 slots
  const int xcd = orig & 7;
  const int slot = orig >> 3;                  // 0..191
  const bool isQ = slot < 64;
  int b, bn;
  if (isQ) { b = slot >> 3; bn = (slot & 7) * 128; }
  else { int s2 = slot - 64; b = s2 >> 4; bn = (s2 & 15) * 128; }
  const int i = (xcd - b) & 7;                 // m-tile index within batch
  const int bm = b * 1024 + i * 128;

  const int need = isQ ? read_len(l_fr_p, b) : read_len(l_en_p, b);
  if (i * 128 >= need) return;

  const uint16_t* Bw = isQ ? wq : wkv;
  const float* bias = isQ ? bq : bkv;
  const float scale = isQ ? 0.03125f : 1.0f;
  const float* Af = isQ ? frF : enF;

  f32x4 acc[4][4];
#pragma unroll
  for (int ii = 0; ii < 4; ++ii)
#pragma unroll
    for (int j = 0; j < 4; ++j) acc[ii][j] = (f32x4){0.f, 0.f, 0.f, 0.f};

  float4 ar0[4], ar1[4];  // A register staging (f32)

  auto stageB = [&](int buf, int kt) {
#pragma unroll
    for (int ii = 0; ii < 4; ++ii) {
      int g = t + 256 * ii;           // LDS slot granule (16B units)
      int L = g ^ ((g >> 3) & 7);     // logical granule it must hold
      int row = L >> 3, k8 = L & 7;
      GLDS16(Bw + (size_t)(bn + row) * 1024 + kt + k8 * 8, &Bs[buf][g * 8]);
    }
  };
  auto loadA_f32 = [&](int kt) {
#pragma unroll
    for (int ii = 0; ii < 4; ++ii) {
      int L = t + 256 * ii;
      int row = L >> 3, k8 = L & 7;
      const float* src = Af + (size_t)(bm + row) * 1024 + kt + k8 * 8;
      ar0[ii] = *reinterpret_cast<const float4*>(src);
      ar1[ii] = *reinterpret_cast<const float4*>(src + 4);
    }
  };
  auto writeA = [&](int buf) {
#pragma unroll
    for (int ii = 0; ii < 4; ++ii) {
      int L = t + 256 * ii;
      int row = L >> 3, k8 = L & 7;
      ushortx8 o;
      o[0] = f2bf(ar0[ii].x); o[1] = f2bf(ar0[ii].y);
      o[2] = f2bf(ar0[ii].z); o[3] = f2bf(ar0[ii].w);
      o[4] = f2bf(ar1[ii].x); o[5] = f2bf(ar1[ii].y);
      o[6] = f2bf(ar1[ii].z); o[7] = f2bf(ar1[ii].w);
      int byte = (row * 128 + k8 * 16) ^ ((row & 7) << 4);
      *reinterpret_cast<ushortx8*>(reinterpret_cast<char*>(As[buf]) + byte) = o;
    }
  };
  auto compute = [&](int buf) {
#pragma unroll
    for (int ks = 0; ks < 2; ++ks) {
      const int kb = ks * 64 + lg * 16;  // byte offset within a 128B row
      bf16x8 af[4], bf[4];
#pragma unroll
      for (int mf = 0; mf < 4; ++mf) {
        int row = wm * 64 + mf * 16 + l15;
        int byte = (row * 128 + kb) ^ ((row & 7) << 4);
        af[mf] = *reinterpret_cast<const bf16x8*>(
            reinterpret_cast<const char*>(As[buf]) + byte);
      }
#pragma unroll
      for (int nf = 0; nf < 4; ++nf) {
        int row = wn * 64 + nf * 16 + l15;
        int byte = (row * 128 + kb) ^ ((row & 7) << 4);
        bf[nf] = *reinterpret_cast<const bf16x8*>(
            reinterpret_cast<const char*>(Bs[buf]) + byte);
      }
#pragma unroll
      for (int mf = 0; mf < 4; ++mf)
#pragma unroll
        for (int nf = 0; nf < 4; ++nf)
          acc[mf][nf] = __builtin_amdgcn_mfma_f32_16x16x32_bf16(
              af[mf], bf[nf], acc[mf][nf], 0, 0, 0);
    }
  };

  // ---- prologue: fill buffer 0 with tile 0 ----
  loadA_f32(0);
  stageB(0, 0);
  writeA(0);
  __syncthreads();

  // ---- 2-phase main loop: one barrier per K-step ----
#pragma unroll 2
  for (int tt = 0; tt < 16; ++tt) {
    const int cur = tt & 1;
    const int ktn = (tt + 1) * 64;
    if (tt < 15) { stageB(cur ^ 1, ktn); loadA_f32(ktn); }
    compute(cur);
    if (tt < 15) writeA(cur ^ 1);  // T14: convert+write after compute
    __syncthreads();
  }

  // Epilogue: add bias, scale, scatter bf16 to attention layouts.
#pragma unroll
  for (int mf = 0; mf < 4; ++mf) {
#pragma unroll
    for (int nf = 0; nf < 4; ++nf) {
      int n = bn + wn * 64 + nf * 16 + l15;
      float bv = bias[n];
#pragma unroll
      for (int r = 0; r < 4; ++r) {
        int m = bm + wm * 64 + mf * 16 + lg * 4 + r;
        float v = (acc[mf][nf][r] + bv) * scale;
        uint16_t o = f2bf(v);
        int bb = m >> 10, s = m & 1023;
        if (isQ) {
          int h = n >> 6, d = n & 63;
          Qb[((((bb * 16 + h) << 10) | s) << 6) | d] = o;
        } else if (n < 1024) {
          int h = n >> 6, d = n & 63;
          Kb[((((bb * 16 + h) << 10) | s) << 6) | d] = o;
        } else {
          int n2 = n - 1024;
          int h = n2 >> 6, d = n2 & 63;
          Vb[((((bb * 16 + h) << 6) | d) << 10) | s] = o;
        }
      }
    }
  }
}

// ---------------- Flash attention (unchanged from r12) ----------------
// 1024 blocks x 512 threads (8 waves). QBLK=128: wave w owns rows
// [q0+16w, q0+16w+16). K/V double-buffered (2-phase), defer-max (THR=8).
// Balanced XCD mapping: XCD = h&7 (every XCD gets 2 heads of every batch).
__global__ __launch_bounds__(512) void attn_kernel(
    const uint16_t* __restrict__ Qb,  // [B,H,S,DH] bf16, pre-scaled
    const uint16_t* __restrict__ Kb,  // [B,H,S,DH] bf16
    const uint16_t* __restrict__ Vt,  // [B,H,DH,S] bf16
    const int* __restrict__ l_en_p, const int* __restrict__ l_fr_p,
    float* __restrict__ out) {        // [B,S,D] f32
  __shared__ __attribute__((aligned(16))) uint16_t Ks[2][64 * 64];
  __shared__ __attribute__((aligned(16))) uint16_t Vs[2][64 * 64];
  __shared__ __attribute__((aligned(16))) bf16_t Ps[8][16][72];
  const int t = threadIdx.x;
  const int lane = t & 63, w = t >> 6;          // w in 0..7
  const int l15 = lane & 15, lg = lane >> 4;
  const int orig = blockIdx.x;
  const int xcd = orig & 7;
  const int slot = orig >> 3;                  // 0..127
  const int b = slot >> 4;
  const int rest = slot & 15;
  const int h = xcd + 8 * (rest >> 3);
  const int q0 = (rest & 7) << 7;              // 128-row tile
  const int bh = b * 16 + h;
  const int len_en = read_len(l_en_p, b);
  const int len_fr = read_len(l_fr_p, b);

  if (q0 >= len_fr) {
    for (int i = t; i < 128 * 64; i += 512) {
      int rr = i >> 6, cc = i & 63;
      out[(size_t)(b * 1024 + q0 + rr) * 1024 + h * 64 + cc] = 0.f;
    }
    return;
  }

  const uint16_t* qbase =
      Qb + ((size_t)bh * 1024 + q0 + w * 16 + l15) * 64 + lg * 8;
  const bf16x8 aq0 = *reinterpret_cast<const bf16x8*>(qbase);
  const bf16x8 aq1 = *reinterpret_cast<const bf16x8*>(qbase + 32);

  float mrow[4], lrow[4];
  f32x4 oacc[4];
#pragma unroll
  for (int r = 0; r < 4; ++r) { mrow[r] = -1e30f; lrow[r] = 0.f; }
#pragma unroll
  for (int df = 0; df < 4; ++df) oacc[df] = (f32x4){0.f, 0.f, 0.f, 0.f};

  auto stage = [&](int buf, int j0) {
    int g = t;
    int L = g ^ ((g >> 3) & 7);
    int row = L >> 3, k8 = L & 7;
    GLDS16(Kb + ((size_t)bh * 1024 + j0 + row) * 64 + k8 * 8, &Ks[buf][g * 8]);
    GLDS16(Vt + ((size_t)bh * 64 + row) * 1024 + j0 + k8 * 8, &Vs[buf][g * 8]);
  };

  const int ntiles = (len_en + 63) >> 6;
  stage(0, 0);
  __syncthreads();

  for (int tt = 0; tt < ntiles; ++tt) {
    const int cur = tt & 1;
    const int j0 = tt * 64;
    if (tt + 1 < ntiles) stage(cur ^ 1, (tt + 1) * 64);

    f32x4 sc[4];
#pragma unroll
    for (int nf = 0; nf < 4; ++nf) sc[nf] = (f32x4){0.f, 0.f, 0.f, 0.f};
#pragma unroll
    for (int ks = 0; ks < 2; ++ks) {
      const bf16x8 aq = ks ? aq1 : aq0;
      const int kb = ks * 64 + lg * 16;
#pragma unroll
      for (int nf = 0; nf < 4; ++nf) {
        int row = nf * 16 + l15;
        int byte = (row * 128 + kb) ^ ((row & 7) << 4);
        bf16x8 bk = *reinterpret_cast<const bf16x8*>(
            reinterpret_cast<const char*>(Ks[cur]) + byte);
        sc[nf] = __builtin_amdgcn_mfma_f32_16x16x32_bf16(aq, bk, sc[nf], 0, 0, 0);
      }
    }
#pragma unroll
    for (int nf = 0; nf < 4; ++nf) {
      int col = j0 + nf * 16 + l15;
      if (col >= len_en) sc[nf] = (f32x4){-1e30f, -1e30f, -1e30f, -1e30f};
    }
    float tm[4];
#pragma unroll
    for (int r = 0; r < 4; ++r)
      tm[r] = fmaxf(fmaxf(sc[0][r], sc[1][r]), fmaxf(sc[2][r], sc[3][r]));
#pragma unroll
    for (int off = 1; off < 16; off <<= 1)
#pragma unroll
      for (int r = 0; r < 4; ++r) tm[r] = fmaxf(tm[r], __shfl_xor(tm[r], off));

    bool small = (tm[0] <= mrow[0] + 8.f) && (tm[1] <= mrow[1] + 8.f) &&
                 (tm[2] <= mrow[2] + 8.f) && (tm[3] <= mrow[3] + 8.f);
    if (!__all(small)) {
      float fac[4];
#pragma unroll
      for (int r = 0; r < 4; ++r) {
        float mn = fmaxf(mrow[r], tm[r]);
        fac[r] = __expf(mrow[r] - mn);
        mrow[r] = mn;
      }
#pragma unroll
      for (int r = 0; r < 4; ++r) lrow[r] *= fac[r];
#pragma unroll
      for (int df = 0; df < 4; ++df)
#pragma unroll
        for (int r = 0; r < 4; ++r) oacc[df][r] *= fac[r];
    }
    float ps[4] = {0.f, 0.f, 0.f, 0.f};
#pragma unroll
    for (int nf = 0; nf < 4; ++nf)
#pragma unroll
      for (int r = 0; r < 4; ++r) {
        float p = __expf(sc[nf][r] - mrow[r]);
        ps[r] += p;
        Ps[w][lg * 4 + r][nf * 16 + l15] = (bf16_t)p;
      }
#pragma unroll
    for (int off = 1; off < 16; off <<= 1)
#pragma unroll
      for (int r = 0; r < 4; ++r) ps[r] += __shfl_xor(ps[r], off);
#pragma unroll
    for (int r = 0; r < 4; ++r) lrow[r] += ps[r];

#pragma unroll
    for (int ks = 0; ks < 2; ++ks) {
      const bf16x8 pa = *reinterpret_cast<const bf16x8*>(
          &Ps[w][l15][0] + ks * 32 + lg * 8);
#pragma unroll
      for (int df = 0; df < 4; ++df) {
        int row = df * 16 + l15;
        int byte = (row * 128 + ks * 64 + lg * 16) ^ ((row & 7) << 4);
        bf16x8 bv = *reinterpret_cast<const bf16x8*>(
            reinterpret_cast<const char*>(Vs[cur]) + byte);
        oacc[df] = __builtin_amdgcn_mfma_f32_16x16x32_bf16(pa, bv, oacc[df], 0, 0, 0);
      }
    }
    __syncthreads();
  }

#pragma unroll
  for (int df = 0; df < 4; ++df)
#pragma unroll
    for (int r = 0; r < 4; ++r) {
      int q = q0 + w * 16 + lg * 4 + r;
      float inv = (q < len_fr && lrow[r] > 0.f) ? 1.0f / lrow[r] : 0.f;
      out[(size_t)(b * 1024 + q) * 1024 + h * 64 + df * 16 + l15] =
          oacc[df][r] * inv;
    }
}

// ---------------- launch ----------------
extern "C" void kernel_launch(void* const* d_in, const int* in_sizes, int n_in,
                              void* d_out, int out_size, void* d_ws,
                              size_t ws_size, hipStream_t stream) {
  const float* en = (const float*)d_in[0];
  const float* fr = (const float*)d_in[1];
  const int* l_en = (const int*)d_in[2];
  const int* l_fr = (const int*)d_in[3];
  const float* wq = (const float*)d_in[4];
  const float* bq = (const float*)d_in[5];
  const float* wkv = (const float*)d_in[6];
  const float* bkv = (const float*)d_in[7];
  float* out = (float*)d_out;  // output dtype is FLOAT32

  // Workspace layout (bytes), 56.6 MB total (proven safe since r1):
  // wq_bf 0..2M | wkv_bf 2M..6M | Qbuf 6M..23M | Kbuf 23M..40M | Vtbuf 40M..56.6M
  char* ws = (char*)d_ws;
  uint16_t* wq_bf = (uint16_t*)(ws);
  uint16_t* wkv_bf = (uint16_t*)(ws + 2097152);
  uint16_t* Qbuf = (uint16_t*)(ws + 6291456);
  uint16_t* Kbuf = (uint16_t*)(ws + 23068672);
  uint16_t* Vtbuf = (uint16_t*)(ws + 39845888);

  // Weights-only convert (~12 MB read): (1M+2M)/4 granules = 3072 blocks.
  cvt2_kernel<<<3072, 256, 0, stream>>>(wq, wq_bf, 1048576,
                                        wkv, wkv_bf, 2097152);

  gemm_fused<<<1536, 256, 0, stream>>>(fr, en, wq_bf, wkv_bf, bq, bkv,
                                       l_en, l_fr, Qbuf, Kbuf, Vtbuf);

  attn_kernel<<<1024, 512, 0, stream>>>(Qbuf, Kbuf, Vtbuf, l_en, l_fr, out);
}